// Round 1
// baseline (6320.802 us; speedup 1.0000x reference)
//
#include <hip/hip_runtime.h>
#include <math.h>

#define TB 32
#define TT 1000
#define TD 512
#define TU 5
#define TT1 1001

// d_out float offsets (return order: acoustic, token_num, alphas_t, cif_peak, token_num2)
#define OFF_ACC  0
#define OFF_TOKN 16400384
#define OFF_ALPH 16400416
#define OFF_PEAK 16432448
#define OFF_TOK2 16464480

// ---------------- init: zero partial-dot accumulators + token_num2 ----------------
__global__ __launch_bounds__(256) void kzero(float* araw1, float* araw2, float* tok2) {
    int idx = blockIdx.x * 256 + threadIdx.x;
    int stride = gridDim.x * 256;
    for (int i = idx; i < TB * TT; i += stride) araw1[i] = 0.f;
    for (int i = idx; i < TB * TT * TU; i += stride) araw2[i] = 0.f;
    if (idx < TB) tok2[idx] = 0.f;
}

// ---------------- c2 = b2 + dot(up_b, w2) ----------------
__global__ __launch_bounds__(256) void kc2(const float* __restrict__ up_b, const float* __restrict__ w2,
                                           const float* __restrict__ b2, float* __restrict__ c2out) {
    int tid = threadIdx.x;
    float p = 0.f;
    for (int o = tid; o < TD; o += 256) p += up_b[o] * w2[o];
#pragma unroll
    for (int m = 1; m < 64; m <<= 1) p += __shfl_xor(p, m);
    __shared__ float wsum[4];
    if ((tid & 63) == 0) wsum[tid >> 6] = p;
    __syncthreads();
    if (tid == 0) c2out[0] = b2[0] + wsum[0] + wsum[1] + wsum[2] + wsum[3];
}

// ---------------- v[i][j] = sum_o up_w[i][o][j] * w2[o] ----------------
__global__ __launch_bounds__(64) void kv(const float* __restrict__ up_w, const float* __restrict__ w2,
                                         float* __restrict__ vmat) {
    int i = blockIdx.x, lane = threadIdx.x;
    float s0 = 0, s1 = 0, s2 = 0, s3 = 0, s4 = 0;
    for (int o = lane; o < TD; o += 64) {
        float w = w2[o];
        const float* p = up_w + (size_t)i * (TD * TU) + o * TU;
        s0 += p[0] * w; s1 += p[1] * w; s2 += p[2] * w; s3 += p[3] * w; s4 += p[4] * w;
    }
#pragma unroll
    for (int m = 1; m < 64; m <<= 1) {
        s0 += __shfl_xor(s0, m); s1 += __shfl_xor(s1, m); s2 += __shfl_xor(s2, m);
        s3 += __shfl_xor(s3, m); s4 += __shfl_xor(s4, m);
    }
    if (lane == 0) {
        float* d = vmat + i * TU;
        d[0] = s0; d[1] = s1; d[2] = s2; d[3] = s3; d[4] = s4;
    }
}

// ---------------- fused conv1d(K=3,pad=1)+bias+relu, reduced into 6 dots per (b,t) ----------------
// Tile: 64 out-channels x 128 frames per block, per-thread 4o x 8t register tile.
// conv[b,o,t] = sum_{i,k} cw[o,i,k] * enc[b, t+k-1, i]  (zero-padded in t)
__global__ __launch_bounds__(256, 2) void kconv(const float* __restrict__ enc, const float* __restrict__ cw,
                                                const float* __restrict__ cb, const float* __restrict__ w1,
                                                const float* __restrict__ vmat,
                                                float* __restrict__ araw1, float* __restrict__ araw2) {
    __shared__ float sA[16 * 3 * 64];   // [ii][k][o]
    __shared__ float sX[16 * 132];      // [ii][s], s in [0,130), row stride 132 (16B-align + conflict break)

    const int tid = threadIdx.x;
    const int otr = tid & 15;           // 16 o-groups of 4
    const int ttr = tid >> 4;           // 16 t-groups of 8
    const int b = blockIdx.z;
    const int o0 = blockIdx.y * 64;
    const int t0 = blockIdx.x * 128;

    float acc[4][8];
#pragma unroll
    for (int a = 0; a < 4; ++a)
#pragma unroll
        for (int j = 0; j < 8; ++j) acc[a][j] = 0.f;

    const int o_l = tid >> 2, m4 = tid & 3;     // cw staging map
    const int ii_s = tid & 15, s_b = tid >> 4;  // enc staging map

    for (int i0 = 0; i0 < TD; i0 += 16) {
        __syncthreads();
        // stage cw tile: 64 o x 16 i x 3 k ; per-o the 48 floats are contiguous (k fastest)
        {
            const float* src = cw + (size_t)(o0 + o_l) * (TD * 3) + i0 * 3 + m4 * 12;
            float4 c0 = *(const float4*)(src);
            float4 c1 = *(const float4*)(src + 4);
            float4 c2v = *(const float4*)(src + 8);
            float vals[12] = {c0.x, c0.y, c0.z, c0.w, c1.x, c1.y, c1.z, c1.w, c2v.x, c2v.y, c2v.z, c2v.w};
#pragma unroll
            for (int e = 0; e < 12; ++e) sA[(m4 * 12 + e) * 64 + o_l] = vals[e];
        }
        // stage enc tile: rows t0-1 .. t0+128 (130 rows) x 16 channels, zero-padded
#pragma unroll
        for (int p = 0; p < 9; ++p) {
            int s = p * 16 + s_b;
            if (s < 130) {
                int t = t0 - 1 + s;
                float vvv = 0.f;
                if (t >= 0 && t < TT) vvv = enc[((size_t)b * TT + t) * TD + i0 + ii_s];
                sX[ii_s * 132 + s] = vvv;
            }
        }
        __syncthreads();
#pragma unroll
        for (int ii = 0; ii < 16; ++ii) {
            float4 ak0 = *(const float4*)&sA[(ii * 3 + 0) * 64 + (otr << 2)];
            float4 ak1 = *(const float4*)&sA[(ii * 3 + 1) * 64 + (otr << 2)];
            float4 ak2 = *(const float4*)&sA[(ii * 3 + 2) * 64 + (otr << 2)];
            const float* xr = &sX[ii * 132 + (ttr << 3)];
            float4 e0 = *(const float4*)(xr);
            float4 e1 = *(const float4*)(xr + 4);
            float2 e2 = *(const float2*)(xr + 8);
            float e_[10] = {e0.x, e0.y, e0.z, e0.w, e1.x, e1.y, e1.z, e1.w, e2.x, e2.y};
            float a0_[4] = {ak0.x, ak0.y, ak0.z, ak0.w};
            float a1_[4] = {ak1.x, ak1.y, ak1.z, ak1.w};
            float a2_[4] = {ak2.x, ak2.y, ak2.z, ak2.w};
#pragma unroll
            for (int oo = 0; oo < 4; ++oo)
#pragma unroll
                for (int j = 0; j < 8; ++j)
                    acc[oo][j] += a0_[oo] * e_[j] + a1_[oo] * e_[j + 1] + a2_[oo] * e_[j + 2];
        }
    }

    // epilogue: bias+relu, weight by w1 / v[:,0..4], reduce over the 64 o of this block, atomic-add partials
    float cbv[4], w1v[4], vv_[4][5];
#pragma unroll
    for (int oo = 0; oo < 4; ++oo) {
        int o = o0 + (otr << 2) + oo;
        cbv[oo] = cb[o];
        w1v[oo] = w1[o];
#pragma unroll
        for (int q = 0; q < 5; ++q) vv_[oo][q] = vmat[o * 5 + q];
    }
    const int t_base = t0 + (ttr << 3);
#pragma unroll
    for (int j = 0; j < 8; ++j) {
        float s1 = 0.f, s2[5] = {0, 0, 0, 0, 0};
#pragma unroll
        for (int oo = 0; oo < 4; ++oo) {
            float r = fmaxf(acc[oo][j] + cbv[oo], 0.f);
            s1 += w1v[oo] * r;
#pragma unroll
            for (int q = 0; q < 5; ++q) s2[q] += vv_[oo][q] * r;
        }
        // reduce across the 16 otr lanes (low 4 lane bits)
#pragma unroll
        for (int m = 1; m <= 8; m <<= 1) {
            s1 += __shfl_xor(s1, m);
#pragma unroll
            for (int q = 0; q < 5; ++q) s2[q] += __shfl_xor(s2[q], m);
        }
        int t = t_base + j;
        if (otr == 0 && t < TT) {
            atomicAdd(&araw1[b * TT + t], s1);
#pragma unroll
            for (int q = 0; q < 5; ++q) atomicAdd(&araw2[(b * TT + t) * 5 + q], s2[q]);
        }
    }
}

// ---------------- alphas_t (with tail), token_num2 ----------------
__global__ __launch_bounds__(256) void kalpha(const float* __restrict__ araw1, const float* __restrict__ araw2,
                                              const float* __restrict__ mask, const float* __restrict__ b1,
                                              const float* __restrict__ c2,
                                              float* __restrict__ alphas_t, float* __restrict__ tok2) {
    int b = blockIdx.y;
    int t = blockIdx.x * 256 + threadIdx.x;
    float sum5 = 0.f;
    if (t < TT) {
        float mk = mask[b * TT + t];
        float a1 = araw1[b * TT + t] + b1[0];
        float alpha = mk / (1.f + expf(-a1));
        float mprev = (t == 0) ? 1.f : mask[b * TT + t - 1];
        float tail = (mprev - mk) * 0.45f;
        alphas_t[b * TT1 + t] = alpha + tail;
        float cc = c2[0];
#pragma unroll
        for (int q = 0; q < 5; ++q) {
            float x = araw2[(b * TT + t) * 5 + q] + cc;
            sum5 += mk / (1.f + expf(-x));
        }
    } else if (t == TT) {
        alphas_t[b * TT1 + TT] = mask[b * TT + TT - 1] * 0.45f;
    }
#pragma unroll
    for (int m = 1; m < 64; m <<= 1) sum5 += __shfl_xor(sum5, m);
    if ((threadIdx.x & 63) == 0) atomicAdd(&tok2[b], sum5);
}

// ---------------- sequential CIF scan (faithful to reference fp32 op order) ----------------
// One block per batch. A wave loads 64 alphas coalesced; all lanes redundantly run the serial
// recurrence via shfl-broadcast; lane j records per-t outputs -> coalesced writes.
__global__ __launch_bounds__(64) void kscan(const float* __restrict__ alphas_t,
                                            float* __restrict__ cif_peak, float* __restrict__ token_num,
                                            float* __restrict__ wA, float* __restrict__ wB,
                                            int* __restrict__ fire_time, int* __restrict__ n_fires) {
    int b = blockIdx.x, lane = threadIdx.x;
    float integ = 0.f, Ssum = 0.f;
    int F = 0;
    for (int c = 0; c < 16; ++c) {
        int t = c * 64 + lane;
        float av = (t < TT1) ? alphas_t[b * TT1 + t] : 0.f;
        float myPeak = 0.f, myWA = 0.f, myWB = 0.f;
        int myFire = 0, myF = 0;
        for (int j = 0; j < 64; ++j) {
            float a = __shfl(av, j);
            if (c * 64 + j < TT1) {
                float dist = 1.f - integ;
                integ += a;
                float peak = integ;
                bool fire = integ >= 1.f;
                float cur = fire ? dist : a;
                if (lane == j) {
                    myPeak = peak;
                    myWA = cur;                       // weight into current slot
                    myWB = fire ? (a - cur) : 0.f;    // leftover into next slot
                    myFire = fire ? 1 : 0;
                    myF = F;                          // fire index BEFORE this fire
                }
                if (fire) { integ -= 1.f; F++; }
                Ssum += a;
            }
        }
        if (t < TT1) {
            cif_peak[b * TT1 + t] = myPeak;
            wA[b * TT1 + t] = myWA;
            wB[b * TT1 + t] = myWB;
            if (myFire) fire_time[b * TT1 + myF] = t;
        }
    }
    if (lane == 0) {
        token_num[b] = floorf(Ssum);
        n_fires[b] = F;
    }
}

// ---------------- gather: acoustic[b,k,:] = segmented weighted sum of encoder rows ----------------
__global__ __launch_bounds__(128) void kgather(const float* __restrict__ enc,
                                               const float* __restrict__ wA, const float* __restrict__ wB,
                                               const int* __restrict__ fire_time, const int* __restrict__ n_fires,
                                               float* __restrict__ acoustic) {
    int k = blockIdx.x, b = blockIdx.y;
    int d4 = threadIdx.x;  // float4 index over D=512
    float ox = 0.f, oy = 0.f, oz = 0.f, ow = 0.f;
    int nf = n_fires[b];
    if (k < nf) {
        int end = fire_time[b * TT1 + k];
        int start = (k > 0) ? fire_time[b * TT1 + k - 1] : 0;
        for (int t = start; t <= end; ++t) {
            if (t >= TT) continue;  // hidden row T is all-zero
            float w = (k > 0 && t == start) ? wB[b * TT1 + t] : wA[b * TT1 + t];
            float4 h = ((const float4*)(enc + ((size_t)b * TT + t) * TD))[d4];
            ox += w * h.x; oy += w * h.y; oz += w * h.z; ow += w * h.w;
        }
    }
    float4 o4; o4.x = ox; o4.y = oy; o4.z = oz; o4.w = ow;
    ((float4*)(acoustic + ((size_t)b * TT1 + k) * TD))[d4] = o4;
}

extern "C" void kernel_launch(void* const* d_in, const int* in_sizes, int n_in,
                              void* d_out, int out_size, void* d_ws, size_t ws_size,
                              hipStream_t stream) {
    (void)in_sizes; (void)n_in; (void)out_size; (void)ws_size;
    const float* enc = (const float*)d_in[0];
    const float* mask = (const float*)d_in[1];
    const float* cw = (const float*)d_in[2];
    const float* cb = (const float*)d_in[3];
    const float* upw = (const float*)d_in[4];
    const float* upb = (const float*)d_in[5];
    const float* w1 = (const float*)d_in[6];
    const float* b1 = (const float*)d_in[7];
    const float* w2 = (const float*)d_in[8];
    const float* b2 = (const float*)d_in[9];

    float* out = (float*)d_out;
    float* acoustic = out + OFF_ACC;
    float* token_num = out + OFF_TOKN;
    float* alphas_t = out + OFF_ALPH;
    float* cif_peak = out + OFF_PEAK;
    float* tok2 = out + OFF_TOK2;

    float* ws = (float*)d_ws;
    float* araw1 = ws;                       // 32*1000
    float* araw2 = araw1 + TB * TT;          // 32*1000*5
    float* vmat = araw2 + TB * TT * TU;      // 512*5
    float* c2 = vmat + TD * TU;              // 1 (pad to 4)
    float* wA = c2 + 4;                      // 32*1001
    float* wB = wA + TB * TT1;               // 32*1001
    int* fire_time = (int*)(wB + TB * TT1);  // 32*1001
    int* n_fires = fire_time + TB * TT1;     // 32

    hipLaunchKernelGGL(kzero, dim3(256), dim3(256), 0, stream, araw1, araw2, tok2);
    hipLaunchKernelGGL(kc2, dim3(1), dim3(256), 0, stream, upb, w2, b2, c2);
    hipLaunchKernelGGL(kv, dim3(TD), dim3(64), 0, stream, upw, w2, vmat);
    hipLaunchKernelGGL(kconv, dim3(8, 8, TB), dim3(256), 0, stream, enc, cw, cb, w1, vmat, araw1, araw2);
    hipLaunchKernelGGL(kalpha, dim3(4, TB), dim3(256), 0, stream, araw1, araw2, mask, b1, c2, alphas_t, tok2);
    hipLaunchKernelGGL(kscan, dim3(TB), dim3(64), 0, stream, alphas_t, cif_peak, token_num, wA, wB, fire_time, n_fires);
    hipLaunchKernelGGL(kgather, dim3(TT1, TB), dim3(128), 0, stream, enc, wA, wB, fire_time, n_fires, acoustic);
}

// Round 2
// 949.245 us; speedup vs baseline: 6.6588x; 6.6588x over previous
//
#include <hip/hip_runtime.h>
#include <math.h>

#define TB 32
#define TT 1000
#define TD 512
#define TU 5
#define TT1 1001

// d_out float offsets (return order: acoustic, token_num, alphas_t, cif_peak, token_num2)
#define OFF_ACC  0
#define OFF_TOKN 16400384
#define OFF_ALPH 16400416
#define OFF_PEAK 16432448
#define OFF_TOK2 16464480

// ---------------- init: zero partial-dot accumulators + token_num2 ----------------
__global__ __launch_bounds__(256) void kzero(float* araw1, float* araw2, float* tok2) {
    int idx = blockIdx.x * 256 + threadIdx.x;
    int stride = gridDim.x * 256;
    for (int i = idx; i < TB * TT; i += stride) araw1[i] = 0.f;
    for (int i = idx; i < TB * TT * TU; i += stride) araw2[i] = 0.f;
    if (idx < TB) tok2[idx] = 0.f;
}

// ---------------- c2 = b2 + dot(up_b, w2) ----------------
__global__ __launch_bounds__(256) void kc2(const float* __restrict__ up_b, const float* __restrict__ w2,
                                           const float* __restrict__ b2, float* __restrict__ c2out) {
    int tid = threadIdx.x;
    float p = 0.f;
    for (int o = tid; o < TD; o += 256) p += up_b[o] * w2[o];
#pragma unroll
    for (int m = 1; m < 64; m <<= 1) p += __shfl_xor(p, m);
    __shared__ float wsum[4];
    if ((tid & 63) == 0) wsum[tid >> 6] = p;
    __syncthreads();
    if (tid == 0) c2out[0] = b2[0] + wsum[0] + wsum[1] + wsum[2] + wsum[3];
}

// ---------------- v[i][j] = sum_o up_w[i][o][j] * w2[o] ----------------
__global__ __launch_bounds__(64) void kv(const float* __restrict__ up_w, const float* __restrict__ w2,
                                         float* __restrict__ vmat) {
    int i = blockIdx.x, lane = threadIdx.x;
    float s0 = 0, s1 = 0, s2 = 0, s3 = 0, s4 = 0;
    for (int o = lane; o < TD; o += 64) {
        float w = w2[o];
        const float* p = up_w + (size_t)i * (TD * TU) + o * TU;
        s0 += p[0] * w; s1 += p[1] * w; s2 += p[2] * w; s3 += p[3] * w; s4 += p[4] * w;
    }
#pragma unroll
    for (int m = 1; m < 64; m <<= 1) {
        s0 += __shfl_xor(s0, m); s1 += __shfl_xor(s1, m); s2 += __shfl_xor(s2, m);
        s3 += __shfl_xor(s3, m); s4 += __shfl_xor(s4, m);
    }
    if (lane == 0) {
        float* d = vmat + i * TU;
        d[0] = s0; d[1] = s1; d[2] = s2; d[3] = s3; d[4] = s4;
    }
}

// ---------------- fused conv1d(K=3,pad=1)+bias+relu, reduced into 6 dots per (b,t) ----------------
// Tile: 64 out-channels x 128 frames per block, per-thread 4o x 8t register tile.
// ALL scalars explicitly named -> no local arrays -> no scratch spill possible.
#define ROW(j, XJ, XJ1, XJ2) \
    c0##j += a0.x * (XJ) + a1.x * (XJ1) + a2.x * (XJ2); \
    c1##j += a0.y * (XJ) + a1.y * (XJ1) + a2.y * (XJ2); \
    c2##j += a0.z * (XJ) + a1.z * (XJ1) + a2.z * (XJ2); \
    c3##j += a0.w * (XJ) + a1.w * (XJ1) + a2.w * (XJ2);

#define EPI(jlit, A0, A1, A2, A3) { \
    float r0 = fmaxf((A0) + cb0, 0.f); \
    float r1 = fmaxf((A1) + cb1, 0.f); \
    float r2 = fmaxf((A2) + cb2, 0.f); \
    float r3 = fmaxf((A3) + cb3, 0.f); \
    float s1 = w10 * r0 + w11 * r1 + w12 * r2 + w13 * r3; \
    float sa = v0a * r0 + v1a * r1 + v2a * r2 + v3a * r3; \
    float sb = v0b * r0 + v1b * r1 + v2b * r2 + v3b * r3; \
    float sc = v0c * r0 + v1c * r1 + v2c * r2 + v3c * r3; \
    float sd = v0d * r0 + v1d * r1 + v2d * r2 + v3d * r3; \
    float se = v0e * r0 + v1e * r1 + v2e * r2 + v3e * r3; \
    s1 += __shfl_xor(s1, 1); sa += __shfl_xor(sa, 1); sb += __shfl_xor(sb, 1); \
    sc += __shfl_xor(sc, 1); sd += __shfl_xor(sd, 1); se += __shfl_xor(se, 1); \
    s1 += __shfl_xor(s1, 2); sa += __shfl_xor(sa, 2); sb += __shfl_xor(sb, 2); \
    sc += __shfl_xor(sc, 2); sd += __shfl_xor(sd, 2); se += __shfl_xor(se, 2); \
    s1 += __shfl_xor(s1, 4); sa += __shfl_xor(sa, 4); sb += __shfl_xor(sb, 4); \
    sc += __shfl_xor(sc, 4); sd += __shfl_xor(sd, 4); se += __shfl_xor(se, 4); \
    s1 += __shfl_xor(s1, 8); sa += __shfl_xor(sa, 8); sb += __shfl_xor(sb, 8); \
    sc += __shfl_xor(sc, 8); sd += __shfl_xor(sd, 8); se += __shfl_xor(se, 8); \
    int t = t_base + (jlit); \
    if (otr == 0 && t < TT) { \
        atomicAdd(&araw1[b * TT + t], s1); \
        float* p2 = &araw2[(b * TT + t) * 5]; \
        atomicAdd(p2 + 0, sa); atomicAdd(p2 + 1, sb); atomicAdd(p2 + 2, sc); \
        atomicAdd(p2 + 3, sd); atomicAdd(p2 + 4, se); } }

__global__ __launch_bounds__(256) void kconv(const float* __restrict__ enc, const float* __restrict__ cw,
                                             const float* __restrict__ cb, const float* __restrict__ w1,
                                             const float* __restrict__ vmat,
                                             float* __restrict__ araw1, float* __restrict__ araw2) {
    __shared__ float sA[16 * 3 * 64];   // [i][k][o]   (i*3+k)*64 + o
    __shared__ float sX[16 * 132];      // [i][s], s in [0,130), row stride 132

    const int tid = threadIdx.x;
    const int otr = tid & 15;           // 16 o-groups of 4
    const int ttr = tid >> 4;           // 16 t-groups of 8
    const int b = blockIdx.z;
    const int o0 = blockIdx.y * 64;
    const int t0 = blockIdx.x * 128;

    float c00 = 0, c01 = 0, c02 = 0, c03 = 0, c04 = 0, c05 = 0, c06 = 0, c07 = 0;
    float c10 = 0, c11 = 0, c12 = 0, c13 = 0, c14 = 0, c15 = 0, c16 = 0, c17 = 0;
    float c20 = 0, c21 = 0, c22 = 0, c23 = 0, c24 = 0, c25 = 0, c26 = 0, c27 = 0;
    float c30 = 0, c31 = 0, c32 = 0, c33 = 0, c34 = 0, c35 = 0, c36 = 0, c37 = 0;

    const int o_l = tid >> 2, m4 = tid & 3;  // cw staging map

    for (int i0 = 0; i0 < TD; i0 += 16) {
        __syncthreads();
        // stage cw tile: 64 o x 16 i x 3 k ; per-o the 48 floats are contiguous (k fastest)
        {
            const float* src = cw + (size_t)(o0 + o_l) * (TD * 3) + i0 * 3 + m4 * 12;
            float4 q0 = *(const float4*)(src);
            float4 q1 = *(const float4*)(src + 4);
            float4 q2 = *(const float4*)(src + 8);
            float* d = &sA[(m4 * 12) * 64 + o_l];
            d[0]   = q0.x; d[64]  = q0.y; d[128] = q0.z; d[192] = q0.w;
            d[256] = q1.x; d[320] = q1.y; d[384] = q1.z; d[448] = q1.w;
            d[512] = q2.x; d[576] = q2.y; d[640] = q2.z; d[704] = q2.w;
        }
        // stage enc tile: rows t0-1 .. t0+128 (130 rows) x 16 channels, float4 loads, transposed store
        for (int idx = tid; idx < 520; idx += 256) {
            int s = idx >> 2;       // 0..129
            int c4 = idx & 3;       // channel quad
            int t = t0 - 1 + s;
            float4 v = make_float4(0.f, 0.f, 0.f, 0.f);
            if (t >= 0 && t < TT) v = *(const float4*)&enc[((size_t)b * TT + t) * TD + i0 + c4 * 4];
            float* d = &sX[(c4 * 4) * 132 + s];
            d[0] = v.x; d[132] = v.y; d[264] = v.z; d[396] = v.w;
        }
        __syncthreads();
        for (int ii = 0; ii < 16; ++ii) {
            const float* aB = &sA[ii * 192 + (otr << 2)];
            float4 a0 = *(const float4*)(aB);
            float4 a1 = *(const float4*)(aB + 64);
            float4 a2 = *(const float4*)(aB + 128);
            const float* xr = &sX[ii * 132 + (ttr << 3)];
            float4 xA = *(const float4*)(xr);
            float4 xB = *(const float4*)(xr + 4);
            float2 xC = *(const float2*)(xr + 8);
            ROW(0, xA.x, xA.y, xA.z)
            ROW(1, xA.y, xA.z, xA.w)
            ROW(2, xA.z, xA.w, xB.x)
            ROW(3, xA.w, xB.x, xB.y)
            ROW(4, xB.x, xB.y, xB.z)
            ROW(5, xB.y, xB.z, xB.w)
            ROW(6, xB.z, xB.w, xC.x)
            ROW(7, xB.w, xC.x, xC.y)
        }
    }

    // epilogue: bias+relu, weight by w1 / v[:,0..4], reduce over the 64 o of this block
    const int ob = o0 + (otr << 2);
    float cb0 = cb[ob + 0], cb1 = cb[ob + 1], cb2 = cb[ob + 2], cb3 = cb[ob + 3];
    float w10 = w1[ob + 0], w11 = w1[ob + 1], w12 = w1[ob + 2], w13 = w1[ob + 3];
    const float* vp0 = vmat + (ob + 0) * 5;
    const float* vp1 = vmat + (ob + 1) * 5;
    const float* vp2 = vmat + (ob + 2) * 5;
    const float* vp3 = vmat + (ob + 3) * 5;
    float v0a = vp0[0], v0b = vp0[1], v0c = vp0[2], v0d = vp0[3], v0e = vp0[4];
    float v1a = vp1[0], v1b = vp1[1], v1c = vp1[2], v1d = vp1[3], v1e = vp1[4];
    float v2a = vp2[0], v2b = vp2[1], v2c = vp2[2], v2d = vp2[3], v2e = vp2[4];
    float v3a = vp3[0], v3b = vp3[1], v3c = vp3[2], v3d = vp3[3], v3e = vp3[4];
    const int t_base = t0 + (ttr << 3);
    EPI(0, c00, c10, c20, c30)
    EPI(1, c01, c11, c21, c31)
    EPI(2, c02, c12, c22, c32)
    EPI(3, c03, c13, c23, c33)
    EPI(4, c04, c14, c24, c34)
    EPI(5, c05, c15, c25, c35)
    EPI(6, c06, c16, c26, c36)
    EPI(7, c07, c17, c27, c37)
}

// ---------------- alphas_t (with tail), token_num2 ----------------
__global__ __launch_bounds__(256) void kalpha(const float* __restrict__ araw1, const float* __restrict__ araw2,
                                              const float* __restrict__ mask, const float* __restrict__ b1,
                                              const float* __restrict__ c2,
                                              float* __restrict__ alphas_t, float* __restrict__ tok2) {
    int b = blockIdx.y;
    int t = blockIdx.x * 256 + threadIdx.x;
    float sum5 = 0.f;
    if (t < TT) {
        float mk = mask[b * TT + t];
        float a1 = araw1[b * TT + t] + b1[0];
        float alpha = mk / (1.f + expf(-a1));
        float mprev = (t == 0) ? 1.f : mask[b * TT + t - 1];
        float tail = (mprev - mk) * 0.45f;
        alphas_t[b * TT1 + t] = alpha + tail;
        float cc = c2[0];
        float x0 = araw2[(b * TT + t) * 5 + 0] + cc;
        float x1 = araw2[(b * TT + t) * 5 + 1] + cc;
        float x2 = araw2[(b * TT + t) * 5 + 2] + cc;
        float x3 = araw2[(b * TT + t) * 5 + 3] + cc;
        float x4 = araw2[(b * TT + t) * 5 + 4] + cc;
        sum5 = mk / (1.f + expf(-x0)) + mk / (1.f + expf(-x1)) + mk / (1.f + expf(-x2))
             + mk / (1.f + expf(-x3)) + mk / (1.f + expf(-x4));
    } else if (t == TT) {
        alphas_t[b * TT1 + TT] = mask[b * TT + TT - 1] * 0.45f;
    }
#pragma unroll
    for (int m = 1; m < 64; m <<= 1) sum5 += __shfl_xor(sum5, m);
    if ((threadIdx.x & 63) == 0) atomicAdd(&tok2[b], sum5);
}

// ---------------- sequential CIF scan (faithful to reference fp32 op order) ----------------
__global__ __launch_bounds__(64) void kscan(const float* __restrict__ alphas_t,
                                            float* __restrict__ cif_peak, float* __restrict__ token_num,
                                            float* __restrict__ wA, float* __restrict__ wB,
                                            int* __restrict__ fire_time, int* __restrict__ n_fires) {
    int b = blockIdx.x, lane = threadIdx.x;
    float integ = 0.f, Ssum = 0.f;
    int F = 0;
    for (int c = 0; c < 16; ++c) {
        int t = c * 64 + lane;
        float av = (t < TT1) ? alphas_t[b * TT1 + t] : 0.f;
        float myPeak = 0.f, myWA = 0.f, myWB = 0.f;
        int myFire = 0, myF = 0;
        for (int j = 0; j < 64; ++j) {
            float a = __shfl(av, j);
            if (c * 64 + j < TT1) {
                float dist = 1.f - integ;
                integ += a;
                float peak = integ;
                bool fire = integ >= 1.f;
                float cur = fire ? dist : a;
                if (lane == j) {
                    myPeak = peak;
                    myWA = cur;
                    myWB = fire ? (a - cur) : 0.f;
                    myFire = fire ? 1 : 0;
                    myF = F;
                }
                if (fire) { integ -= 1.f; F++; }
                Ssum += a;
            }
        }
        if (t < TT1) {
            cif_peak[b * TT1 + t] = myPeak;
            wA[b * TT1 + t] = myWA;
            wB[b * TT1 + t] = myWB;
            if (myFire) fire_time[b * TT1 + myF] = t;
        }
    }
    if (lane == 0) {
        token_num[b] = floorf(Ssum);
        n_fires[b] = F;
    }
}

// ---------------- gather: acoustic[b,k,:] = segmented weighted sum of encoder rows ----------------
__global__ __launch_bounds__(128) void kgather(const float* __restrict__ enc,
                                               const float* __restrict__ wA, const float* __restrict__ wB,
                                               const int* __restrict__ fire_time, const int* __restrict__ n_fires,
                                               float* __restrict__ acoustic) {
    int k = blockIdx.x, b = blockIdx.y;
    int d4 = threadIdx.x;
    float ox = 0.f, oy = 0.f, oz = 0.f, ow = 0.f;
    int nf = n_fires[b];
    if (k < nf) {
        int end = fire_time[b * TT1 + k];
        int start = (k > 0) ? fire_time[b * TT1 + k - 1] : 0;
        for (int t = start; t <= end; ++t) {
            if (t >= TT) continue;
            float w = (k > 0 && t == start) ? wB[b * TT1 + t] : wA[b * TT1 + t];
            float4 h = ((const float4*)(enc + ((size_t)b * TT + t) * TD))[d4];
            ox += w * h.x; oy += w * h.y; oz += w * h.z; ow += w * h.w;
        }
    }
    float4 o4; o4.x = ox; o4.y = oy; o4.z = oz; o4.w = ow;
    ((float4*)(acoustic + ((size_t)b * TT1 + k) * TD))[d4] = o4;
}

extern "C" void kernel_launch(void* const* d_in, const int* in_sizes, int n_in,
                              void* d_out, int out_size, void* d_ws, size_t ws_size,
                              hipStream_t stream) {
    (void)in_sizes; (void)n_in; (void)out_size; (void)ws_size;
    const float* enc = (const float*)d_in[0];
    const float* mask = (const float*)d_in[1];
    const float* cw = (const float*)d_in[2];
    const float* cb = (const float*)d_in[3];
    const float* upw = (const float*)d_in[4];
    const float* upb = (const float*)d_in[5];
    const float* w1 = (const float*)d_in[6];
    const float* b1 = (const float*)d_in[7];
    const float* w2 = (const float*)d_in[8];
    const float* b2 = (const float*)d_in[9];

    float* out = (float*)d_out;
    float* acoustic = out + OFF_ACC;
    float* token_num = out + OFF_TOKN;
    float* alphas_t = out + OFF_ALPH;
    float* cif_peak = out + OFF_PEAK;
    float* tok2 = out + OFF_TOK2;

    float* ws = (float*)d_ws;
    float* araw1 = ws;                       // 32*1000
    float* araw2 = araw1 + TB * TT;          // 32*1000*5
    float* vmat = araw2 + TB * TT * TU;      // 512*5
    float* c2 = vmat + TD * TU;              // 1 (pad to 4)
    float* wA = c2 + 4;                      // 32*1001
    float* wB = wA + TB * TT1;               // 32*1001
    int* fire_time = (int*)(wB + TB * TT1);  // 32*1001
    int* n_fires = fire_time + TB * TT1;     // 32

    hipLaunchKernelGGL(kzero, dim3(256), dim3(256), 0, stream, araw1, araw2, tok2);
    hipLaunchKernelGGL(kc2, dim3(1), dim3(256), 0, stream, upb, w2, b2, c2);
    hipLaunchKernelGGL(kv, dim3(TD), dim3(64), 0, stream, upw, w2, vmat);
    hipLaunchKernelGGL(kconv, dim3(8, 8, TB), dim3(256), 0, stream, enc, cw, cb, w1, vmat, araw1, araw2);
    hipLaunchKernelGGL(kalpha, dim3(4, TB), dim3(256), 0, stream, araw1, araw2, mask, b1, c2, alphas_t, tok2);
    hipLaunchKernelGGL(kscan, dim3(TB), dim3(64), 0, stream, alphas_t, cif_peak, token_num, wA, wB, fire_time, n_fires);
    hipLaunchKernelGGL(kgather, dim3(TT1, TB), dim3(128), 0, stream, enc, wA, wB, fire_time, n_fires, acoustic);
}